// Round 3
// baseline (122.160 us; speedup 1.0000x reference)
//
#include <hip/hip_runtime.h>

#define NN 8192
#define DD 256    // 512 bytes per bf16 row
#define LDSB 65536

typedef __bf16 bf16x8 __attribute__((ext_vector_type(8)));
typedef float  f32x4  __attribute__((ext_vector_type(4)));

__device__ __forceinline__ unsigned short f2bf(float f) {
    unsigned u = __float_as_uint(f);
    return (unsigned short)((u + 0x7fffu + ((u >> 16) & 1u)) >> 16);
}

__device__ __forceinline__ void gload16(const void* g, void* l) {
    __builtin_amdgcn_global_load_lds((const __attribute__((address_space(1))) void*)g,
                                     (__attribute__((address_space(3))) void*)l,
                                     16, 0, 0);
}

__device__ __forceinline__ void barsync() {
    asm volatile("" ::: "memory");
    __builtin_amdgcn_s_barrier();
    asm volatile("" ::: "memory");
}

// ---------------- kernel 1: normalize rows -> bf16, zero rowsum ----------------
__global__ __launch_bounds__(256) void ntxent_norm(const float* __restrict__ z,
                                                   char* __restrict__ znB,
                                                   float* __restrict__ rowsum)
{
    const int t = threadIdx.x;
    const int l = t & 63;
    const int w = t >> 6;
    const int row = blockIdx.x * 4 + w;

    float4 v = ((const float4*)(z + (size_t)row * DD))[l];
    float ss = v.x * v.x + v.y * v.y + v.z * v.z + v.w * v.w;
    ss += __shfl_xor(ss, 1);  ss += __shfl_xor(ss, 2);  ss += __shfl_xor(ss, 4);
    ss += __shfl_xor(ss, 8);  ss += __shfl_xor(ss, 16); ss += __shfl_xor(ss, 32);
    const float inv = 1.0f / fmaxf(sqrtf(ss), 1e-8f);

    uint2 o;
    o.x = (unsigned)f2bf(v.x * inv) | ((unsigned)f2bf(v.y * inv) << 16);
    o.y = (unsigned)f2bf(v.z * inv) | ((unsigned)f2bf(v.w * inv) << 16);
    ((uint2*)(znB + (size_t)row * 512))[l] = o;

    if (blockIdx.x < 32) rowsum[blockIdx.x * 256 + t] = 0.0f;
}

// ---------------- kernel 2: fused 256x256-tile 8-phase sim GEMM + exp ----------------
// grid 32x32=1024 blocks, 512 threads (8 waves, 2Mx4N), LDS 128 KB.
// LDS layout per dbuf b: [op A=0/B=1][khalf kw] slots of 16 KB (256 rows x 64 B),
// 16B-unit involution swizzle pi(u)=u^((u>>2)&7), applied on global SOURCE at stage
// and on LDS address at read (both-sides).
__global__ __launch_bounds__(512, 2) void ntxent_sim(const char* __restrict__ znB,
                                                     float* __restrict__ rowsum,
                                                     float* __restrict__ possum)
{
    __shared__ char lds[131072];

    const int tid = threadIdx.x;
    const int l  = tid & 63;
    const int w  = tid >> 6;    // 0..7
    const int wr = w >> 2;      // 0..1 : row half (128 rows)
    const int wc = w & 3;       // 0..3 : col quarter (64 cols)
    const int lm = l & 15;
    const int lh = l >> 4;      // 0..3

    const int rt = blockIdx.x >> 5;
    const int ct = blockIdx.x & 31;
    const int rowbase = rt * 256;
    const int colbase = ct * 256;

    // ---- stage one half-slot (16 KB): 2 x gload16 per thread, pre-swizzled source
    auto STAGE = [&](int b, int op, int kw, int kt, int gbase) {
#pragma unroll
        for (int p = 0; p < 2; ++p) {
            const int d = p * 512 + tid;
            const int u = d ^ ((d >> 2) & 7);          // involution
            const int row = u >> 2, sub = u & 3;
            gload16(znB + (size_t)(gbase + row) * 512 + kt * 128 + kw * 64 + sub * 16,
                    lds + b * LDSB + op * 32768 + kw * 16384 + d * 16);
        }
    };

    bf16x8 af[8], bfr[2];
    auto LDA = [&](int b, int kw) {
#pragma unroll
        for (int s = 0; s < 8; ++s) {
            const int row = wr * 128 + s * 16 + lm;
            const int u = (row << 2) | lh;
            af[s] = *(const bf16x8*)(lds + b * LDSB + kw * 16384 + ((u ^ (row & 7)) << 4));
        }
    };
    auto LDB = [&](int b, int kw, int ch) {
#pragma unroll
        for (int c = 0; c < 2; ++c) {
            const int row = wc * 64 + ch * 32 + c * 16 + lm;
            const int u = (row << 2) | lh;
            bfr[c] = *(const bf16x8*)(lds + b * LDSB + 32768 + kw * 16384 + ((u ^ (row & 7)) << 4));
        }
    };

    f32x4 acc[8][4];
    const f32x4 vzero = {0.0f, 0.0f, 0.0f, 0.0f};
#pragma unroll
    for (int s = 0; s < 8; ++s)
#pragma unroll
        for (int c = 0; c < 4; ++c) acc[s][c] = vzero;

#define MFMA_PH(CH)                                                                     \
    __builtin_amdgcn_s_setprio(1);                                                      \
    _Pragma("unroll")                                                                   \
    for (int s = 0; s < 8; ++s) {                                                       \
        acc[s][(CH)*2+0] = __builtin_amdgcn_mfma_f32_16x16x32_bf16(af[s], bfr[0], acc[s][(CH)*2+0], 0, 0, 0); \
        acc[s][(CH)*2+1] = __builtin_amdgcn_mfma_f32_16x16x32_bf16(af[s], bfr[1], acc[s][(CH)*2+1], 0, 0, 0); \
    }                                                                                   \
    __builtin_amdgcn_s_setprio(0);

    // prologue: issue tile0 halves in phase order A0,B0,A1,B1 (8 loads outstanding)
    STAGE(0, 0, 0, 0, rowbase);
    STAGE(0, 1, 0, 0, colbase);
    STAGE(0, 0, 1, 0, rowbase);
    STAGE(0, 1, 1, 0, colbase);

#pragma unroll 1
    for (int t = 0; t < 4; ++t) {
        const int b = t & 1, nb = b ^ 1;
        const bool pre = (t < 3);

        // K-tile boundary: A0(t),B0(t) are the oldest 4 loads
        asm volatile("s_waitcnt vmcnt(4)" ::: "memory");
        barsync();

        // P1: kw0, col-half 0   (reads A0,B0; issues A0(t+1))
        LDA(b, 0); LDB(b, 0, 0);
        if (pre) STAGE(nb, 0, 0, t + 1, rowbase);
        barsync();
        MFMA_PH(0)
        barsync();

        // P2: kw0, col-half 1   (reads B0; issues B0(t+1))
        LDB(b, 0, 1);
        if (pre) STAGE(nb, 1, 0, t + 1, colbase);
        barsync();
        MFMA_PH(1)
        // mid-tile boundary: need A1(t),B1(t) (oldest 4 of 8 outstanding)
        if (pre) { asm volatile("s_waitcnt vmcnt(4)" ::: "memory"); }
        else     { asm volatile("s_waitcnt vmcnt(0)" ::: "memory"); }
        barsync();

        // P3: kw1, col-half 0   (reads A1,B1; issues A1(t+1))
        LDA(b, 1); LDB(b, 1, 0);
        if (pre) STAGE(nb, 0, 1, t + 1, rowbase);
        barsync();
        MFMA_PH(0)
        barsync();

        // P4: kw1, col-half 1   (reads B1; issues B1(t+1))
        LDB(b, 1, 1);
        if (pre) STAGE(nb, 1, 1, t + 1, colbase);
        barsync();
        MFMA_PH(1)
        // next loop head (or epilogue) provides the boundary wait+barrier
    }

    // ---------------- epilogue: exp + row sums + positive pairs ----------------
    const bool diag = (rowbase == colbase);
    float psum = 0.0f;
#pragma unroll
    for (int s = 0; s < 8; ++s) {
#pragma unroll
        for (int q = 0; q < 4; ++q) {
            const int i = rowbase + wr * 128 + s * 16 + lh * 4 + q;
            float rs = 0.0f;
#pragma unroll
            for (int c = 0; c < 4; ++c) {
                const int j = colbase + wc * 64 + c * 16 + lm;
                const float lg = 2.0f * acc[s][c][q];
                const float e = __expf(lg);
                rs += (j == i) ? 0.0f : e;
                if (diag) psum += (j == (i ^ 1)) ? lg : 0.0f;
            }
            rs += __shfl_xor(rs, 1); rs += __shfl_xor(rs, 2);
            rs += __shfl_xor(rs, 4); rs += __shfl_xor(rs, 8);
            if (lm == 0) atomicAdd(&rowsum[i], rs);
        }
    }

    // positive-pair block reduce (reuse dead LDS)
    float p = psum;
    p += __shfl_xor(p, 1);  p += __shfl_xor(p, 2);  p += __shfl_xor(p, 4);
    p += __shfl_xor(p, 8);  p += __shfl_xor(p, 16); p += __shfl_xor(p, 32);
    float* psh = (float*)lds;
    __syncthreads();                 // all waves done with buffers
    if (l == 0) psh[w] = p;
    __syncthreads();
    if (tid == 0) {
        float acc8 = 0.0f;
#pragma unroll
        for (int k = 0; k < 8; ++k) acc8 += psh[k];
        possum[blockIdx.x] = acc8;
    }
}

// ---------------- kernel 3: final scalar ----------------
__global__ __launch_bounds__(256) void ntxent_final(const float* __restrict__ rowsum,
                                                    const float* __restrict__ possum,
                                                    float* __restrict__ out)
{
    __shared__ float sh[4];
    const int t = threadIdx.x;
    float s = 0.0f;
#pragma unroll 1
    for (int i = t; i < NN; i += 256) s += __logf(rowsum[i]);
    s -= possum[t] + possum[t + 256] + possum[t + 512] + possum[t + 768];
    s += __shfl_xor(s, 1);  s += __shfl_xor(s, 2);  s += __shfl_xor(s, 4);
    s += __shfl_xor(s, 8);  s += __shfl_xor(s, 16); s += __shfl_xor(s, 32);
    if ((t & 63) == 0) sh[t >> 6] = s;
    __syncthreads();
    if (t == 0) out[0] = (sh[0] + sh[1] + sh[2] + sh[3]) * (1.0f / NN);
}

extern "C" void kernel_launch(void* const* d_in, const int* in_sizes, int n_in,
                              void* d_out, int out_size, void* d_ws, size_t ws_size,
                              hipStream_t stream)
{
    const float* z = (const float*)d_in[0];
    char*  znB    = (char*)d_ws;
    float* rowsum = (float*)((char*)d_ws + (size_t)NN * 512);
    float* possum = (float*)((char*)d_ws + (size_t)NN * 512 + (size_t)NN * 4);
    float* out = (float*)d_out;

    ntxent_norm <<<dim3(NN / 4), dim3(256), 0, stream>>>(z, znB, rowsum);
    ntxent_sim  <<<dim3(1024),   dim3(512), 0, stream>>>(znB, rowsum, possum);
    ntxent_final<<<dim3(1),      dim3(256), 0, stream>>>(rowsum, possum, out);
}

// Round 4
// 100.225 us; speedup vs baseline: 1.2189x; 1.2189x over previous
//
#include <hip/hip_runtime.h>

#define NN 8192
#define DD 256    // 512 bytes per bf16 row

typedef __bf16 bf16x8 __attribute__((ext_vector_type(8)));
typedef float  f32x4  __attribute__((ext_vector_type(4)));

__device__ __forceinline__ unsigned short f2bf(float f) {
    unsigned u = __float_as_uint(f);
    return (unsigned short)((u + 0x7fffu + ((u >> 16) & 1u)) >> 16);
}

__device__ __forceinline__ void gload16(const void* g, void* l) {
    __builtin_amdgcn_global_load_lds((const __attribute__((address_space(1))) void*)g,
                                     (__attribute__((address_space(3))) void*)l,
                                     16, 0, 0);
}

__device__ __forceinline__ void barsync() {
    asm volatile("" ::: "memory");
    __builtin_amdgcn_s_barrier();
    asm volatile("" ::: "memory");
}

// ---------------- kernel 1: normalize rows -> bf16, zero rowsum ----------------
__global__ __launch_bounds__(256) void ntxent_norm(const float* __restrict__ z,
                                                   char* __restrict__ znB,
                                                   float* __restrict__ rowsum)
{
    const int t = threadIdx.x;
    const int l = t & 63;
    const int w = t >> 6;
    const int row = blockIdx.x * 4 + w;

    float4 v = ((const float4*)(z + (size_t)row * DD))[l];
    float ss = v.x * v.x + v.y * v.y + v.z * v.z + v.w * v.w;
    ss += __shfl_xor(ss, 1);  ss += __shfl_xor(ss, 2);  ss += __shfl_xor(ss, 4);
    ss += __shfl_xor(ss, 8);  ss += __shfl_xor(ss, 16); ss += __shfl_xor(ss, 32);
    const float inv = 1.0f / fmaxf(sqrtf(ss), 1e-8f);

    uint2 o;
    o.x = (unsigned)f2bf(v.x * inv) | ((unsigned)f2bf(v.y * inv) << 16);
    o.y = (unsigned)f2bf(v.z * inv) | ((unsigned)f2bf(v.w * inv) << 16);
    ((uint2*)(znB + (size_t)row * 512))[l] = o;

    if (blockIdx.x < 32) rowsum[blockIdx.x * 256 + t] = 0.0f;
}

// ---------------- kernel 2: A-in-registers fused sim GEMM + exp ----------------
// grid 1024 = 64 row-tiles (128 rows) x 16 col-slices (512 cols).
// 512 threads = 8 waves (2M x 4N): wave tile 64 rows x 32 cols per 128-col subtile.
// A (64 rows x K=256 per wave-half) lives in af[4][8] registers, loaded once.
// B: LDS double-buffer 2 x 64 KB (128 cols x 512B), XOR-swizzle unit^=(row&7)
// (key in bits 5+ of unit index, XOR on bits 0-2 -> true involution).
__global__ __launch_bounds__(512, 2) void ntxent_sim(const char* __restrict__ znB,
                                                     float* __restrict__ rowsum,
                                                     float* __restrict__ possum)
{
    __shared__ char lds[131072];

    const int tid = threadIdx.x;
    const int l  = tid & 63;
    const int w  = tid >> 6;
    const int wr = w >> 2;      // 0..1  row half
    const int wc = w & 3;       // 0..3  col quarter (32 cols of 128)
    const int lm = l & 15;
    const int lh = l >> 4;

    const int rt = blockIdx.x >> 4;
    const int js = blockIdx.x & 15;
    const int rowbase = rt * 128;
    const int colbase = js * 512;

    // ---- A fragments: 64 rows x K=256, once, straight from L2 (coalesced 1KB/instr)
    bf16x8 af[4][8];
#pragma unroll
    for (int s = 0; s < 4; ++s) {
        const char* rp = znB + (size_t)(rowbase + wr * 64 + s * 16 + lm) * 512 + lh * 16;
#pragma unroll
        for (int kk = 0; kk < 8; ++kk)
            af[s][kk] = *(const bf16x8*)(rp + kk * 64);
    }

    // ---- stage one 64 KB B-subtile (128 cols x 512 B), 8 x gload16 per thread
    auto STAGE = [&](int buf, int jcb) {
#pragma unroll
        for (int p = 0; p < 8; ++p) {
            const int d = p * 512 + tid;        // 16B-unit index, 0..4095
            const int r = d >> 5;               // LDS row (col of C)
            const int u = d & 31;               // unit within row
            gload16(znB + (size_t)(jcb + r) * 512 + ((u ^ (r & 7)) << 4),
                    lds + buf * 65536 + (d << 4));
        }
    };

    STAGE(0, colbase);            // B0
    STAGE(1, colbase + 128);      // B1

    float rsum[16];
#pragma unroll
    for (int q = 0; q < 16; ++q) rsum[q] = 0.0f;
    float psum = 0.0f;

#pragma unroll 1
    for (int t = 0; t < 4; ++t) {
        const int b = t & 1;
        barsync();                               // buf[(t+1)&1] readers (iter t-1) done
        if (t < 3) STAGE(b ^ 1, colbase + (t + 1) * 128);
        if (t < 3) { asm volatile("s_waitcnt vmcnt(8)" ::: "memory"); }
        else       { asm volatile("s_waitcnt vmcnt(0)" ::: "memory"); }
        barsync();                               // B(t) visible to all waves

        f32x4 acc[4][2];
        const f32x4 vzero = {0.0f, 0.0f, 0.0f, 0.0f};
#pragma unroll
        for (int s = 0; s < 4; ++s) { acc[s][0] = vzero; acc[s][1] = vzero; }

        const char* bbase = lds + b * 65536;
#pragma unroll
        for (int kk = 0; kk < 8; ++kk) {
            bf16x8 bfr[2];
#pragma unroll
            for (int c = 0; c < 2; ++c) {
                const int r = wc * 32 + c * 16 + lm;
                const int u = kk * 4 + lh;
                bfr[c] = *(const bf16x8*)(bbase + r * 512 + ((u ^ (r & 7)) << 4));
            }
#pragma unroll
            for (int s = 0; s < 4; ++s) {
                acc[s][0] = __builtin_amdgcn_mfma_f32_16x16x32_bf16(af[s][kk], bfr[0], acc[s][0], 0, 0, 0);
                acc[s][1] = __builtin_amdgcn_mfma_f32_16x16x32_bf16(af[s][kk], bfr[1], acc[s][1], 0, 0, 0);
            }
        }

        // ---- epilogue (registers only): exp + per-lane row partials
        const int jcb = colbase + t * 128;
        if (jcb == rowbase) {                    // diagonal subtile (64/1024 blocks)
#pragma unroll
            for (int s = 0; s < 4; ++s)
#pragma unroll
                for (int c = 0; c < 2; ++c) {
                    const int j = jcb + wc * 32 + c * 16 + lm;
#pragma unroll
                    for (int q = 0; q < 4; ++q) {
                        const int i = rowbase + wr * 64 + s * 16 + lh * 4 + q;
                        const float lg = 2.0f * acc[s][c][q];
                        rsum[s * 4 + q] += (j == i) ? 0.0f : __expf(lg);
                        psum += (j == (i ^ 1)) ? lg : 0.0f;
                    }
                }
        } else {
#pragma unroll
            for (int s = 0; s < 4; ++s)
#pragma unroll
                for (int c = 0; c < 2; ++c)
#pragma unroll
                    for (int q = 0; q < 4; ++q)
                        rsum[s * 4 + q] += __expf(2.0f * acc[s][c][q]);
        }
    }

    // ---- per-row sums: reduce over the 16 lm lanes, atomic per row
#pragma unroll
    for (int q = 0; q < 16; ++q) {
        float v = rsum[q];
        v += __shfl_xor(v, 1); v += __shfl_xor(v, 2);
        v += __shfl_xor(v, 4); v += __shfl_xor(v, 8);
        rsum[q] = v;
    }
    if (lm == 0) {
#pragma unroll
        for (int s = 0; s < 4; ++s)
#pragma unroll
            for (int q = 0; q < 4; ++q)
                atomicAdd(&rowsum[rowbase + wr * 64 + s * 16 + lh * 4 + q], rsum[s * 4 + q]);
    }

    // ---- positive-pair block reduce (LDS buf0 area is dead now)
    float p = psum;
    p += __shfl_xor(p, 1);  p += __shfl_xor(p, 2);  p += __shfl_xor(p, 4);
    p += __shfl_xor(p, 8);  p += __shfl_xor(p, 16); p += __shfl_xor(p, 32);
    float* psh = (float*)lds;
    if (l == 0) psh[w] = p;
    __syncthreads();
    if (tid == 0) {
        float a8 = 0.0f;
#pragma unroll
        for (int k = 0; k < 8; ++k) a8 += psh[k];
        possum[blockIdx.x] = a8;
    }
}

// ---------------- kernel 3: final scalar ----------------
__global__ __launch_bounds__(512) void ntxent_final(const float* __restrict__ rowsum,
                                                    const float* __restrict__ possum,
                                                    float* __restrict__ out)
{
    __shared__ float sh[8];
    const int t = threadIdx.x;
    float s = 0.0f;
#pragma unroll
    for (int r = 0; r < 16; ++r) s += __logf(rowsum[r * 512 + t]);  // ILP: 16 indep loads
    s -= possum[t] + possum[t + 512];
    s += __shfl_xor(s, 1);  s += __shfl_xor(s, 2);  s += __shfl_xor(s, 4);
    s += __shfl_xor(s, 8);  s += __shfl_xor(s, 16); s += __shfl_xor(s, 32);
    if ((t & 63) == 0) sh[t >> 6] = s;
    __syncthreads();
    if (t == 0) {
        float a = 0.0f;
#pragma unroll
        for (int k = 0; k < 8; ++k) a += sh[k];
        out[0] = a * (1.0f / NN);
    }
}

extern "C" void kernel_launch(void* const* d_in, const int* in_sizes, int n_in,
                              void* d_out, int out_size, void* d_ws, size_t ws_size,
                              hipStream_t stream)
{
    const float* z = (const float*)d_in[0];
    char*  znB    = (char*)d_ws;
    float* rowsum = (float*)((char*)d_ws + (size_t)NN * 512);
    float* possum = (float*)((char*)d_ws + (size_t)NN * 512 + (size_t)NN * 4);
    float* out = (float*)d_out;

    ntxent_norm <<<dim3(NN / 4), dim3(256), 0, stream>>>(z, znB, rowsum);
    ntxent_sim  <<<dim3(1024),   dim3(512), 0, stream>>>(znB, rowsum, possum);
    ntxent_final<<<dim3(1),      dim3(512), 0, stream>>>(rowsum, possum, out);
}

// Round 5
// 77.852 us; speedup vs baseline: 1.5691x; 1.2874x over previous
//
#include <hip/hip_runtime.h>

#define NN 8192
#define DD 256   // 512 bytes per bf16 row

typedef __bf16 bf16x8 __attribute__((ext_vector_type(8)));
typedef float  f32x4  __attribute__((ext_vector_type(4)));

__device__ __forceinline__ unsigned short f2bf(float f) {
    unsigned u = __float_as_uint(f);
    return (unsigned short)((u + 0x7fffu + ((u >> 16) & 1u)) >> 16);
}

__device__ __forceinline__ void gload16(const void* g, void* l) {
    __builtin_amdgcn_global_load_lds((const __attribute__((address_space(1))) void*)g,
                                     (__attribute__((address_space(3))) void*)l,
                                     16, 0, 0);
}

// ---------------- kernel 1: normalize rows -> bf16, zero rowsum ----------------
__global__ __launch_bounds__(256) void ntxent_norm(const float* __restrict__ z,
                                                   char* __restrict__ znB,
                                                   float* __restrict__ rowsum)
{
    const int t = threadIdx.x;
    const int l = t & 63;
    const int w = t >> 6;
    const int row = blockIdx.x * 4 + w;

    float4 v = ((const float4*)(z + (size_t)row * DD))[l];
    float ss = v.x * v.x + v.y * v.y + v.z * v.z + v.w * v.w;
    ss += __shfl_xor(ss, 1);  ss += __shfl_xor(ss, 2);  ss += __shfl_xor(ss, 4);
    ss += __shfl_xor(ss, 8);  ss += __shfl_xor(ss, 16); ss += __shfl_xor(ss, 32);
    const float inv = 1.0f / fmaxf(sqrtf(ss), 1e-8f);

    uint2 o;
    o.x = (unsigned)f2bf(v.x * inv) | ((unsigned)f2bf(v.y * inv) << 16);
    o.y = (unsigned)f2bf(v.z * inv) | ((unsigned)f2bf(v.w * inv) << 16);
    ((uint2*)(znB + (size_t)row * 512))[l] = o;

    if (blockIdx.x < 32) rowsum[blockIdx.x * 256 + t] = 0.0f;
}

// ---------------- kernel 2: symmetric lower-triangle fused sim GEMM + exp ----------------
// grid 2080 = lower triangle of 64x64 tiles of 128x128. Each off-diag block
// contributes e_ij to rowsum_i (row reduce) AND rowsum_j (col reduce) — halves
// the GEMM + exp work. Diagonal blocks: full tile, row sums only, self-mask,
// positive pairs. Inner machinery is R1's proven 2-barrier 128x128/BK=64 layout
// (XOR-swizzled, measured 0 bank conflicts).
__global__ __launch_bounds__(256) void ntxent_sim(const char* __restrict__ znB,
                                                  float* __restrict__ rowsum,
                                                  float* __restrict__ possum)
{
    __shared__ char sA[16384];   // 128 rows x 128B (BK=64 bf16), XOR-swizzled
    __shared__ char sB[16384];
    __shared__ float psh[4];

    const int t  = threadIdx.x;
    const int l  = t & 63;
    const int w  = t >> 6;      // wave 0..3
    const int wr = w >> 1;      // row half
    const int wc = w & 1;       // col half
    const int lm = l & 15;
    const int lh = l >> 4;      // 0..3

    // triangular bid -> (rt, ct), rt >= ct  (block-uniform scalar math)
    const int bid = blockIdx.x;
    int rt = (int)((sqrtf(8.0f * (float)bid + 1.0f) - 1.0f) * 0.5f);
    while ((rt + 1) * (rt + 2) / 2 <= bid) ++rt;
    while (rt * (rt + 1) / 2 > bid) --rt;
    const int ct = bid - rt * (rt + 1) / 2;
    const int rowbase = rt * 128;
    const int colbase = ct * 128;
    const bool diag = (rt == ct);

    const int arow0 = wr * 64;
    const int bcol0 = wc * 64;

    const f32x4 vzero = {0.0f, 0.0f, 0.0f, 0.0f};
    f32x4 acc[4][4];
#pragma unroll
    for (int r = 0; r < 4; ++r)
#pragma unroll
        for (int c = 0; c < 4; ++c) acc[r][c] = vzero;

#pragma unroll 1
    for (int bk = 0; bk < 4; ++bk) {
        __syncthreads();   // all waves done reading sA/sB from previous step
#pragma unroll
        for (int p = 0; p < 4; ++p) {
            const int flat = p * 4096 + t * 16;
            const int row = flat >> 7;
            const int kb  = flat & 127;
            const int skb = (kb ^ ((row & 7) << 4));
            gload16(znB + (size_t)(rowbase + row) * 512 + bk * 128 + skb, sA + flat);
            gload16(znB + (size_t)(colbase + row) * 512 + bk * 128 + skb, sB + flat);
        }
        asm volatile("s_waitcnt vmcnt(0)" ::: "memory");
        __syncthreads();
#pragma unroll
        for (int kw = 0; kw < 2; ++kw) {
            const int kt = kw * 64 + lh * 16;   // byte offset within BK chunk
            bf16x8 af[4], bfr[4];
#pragma unroll
            for (int s = 0; s < 4; ++s) {
                const int ar = arow0 + s * 16 + lm;
                af[s]  = *(const bf16x8*)(sA + ar * 128 + (kt ^ ((ar & 7) << 4)));
                const int bc = bcol0 + s * 16 + lm;
                bfr[s] = *(const bf16x8*)(sB + bc * 128 + (kt ^ ((bc & 7) << 4)));
            }
#pragma unroll
            for (int r = 0; r < 4; ++r)
#pragma unroll
                for (int c = 0; c < 4; ++c)
                    acc[r][c] = __builtin_amdgcn_mfma_f32_16x16x32_bf16(af[r], bfr[c], acc[r][c], 0, 0, 0);
        }
    }

    // ---------------- epilogue: exp, row sums, col sums (symmetry), positives ----
    float rsum[16];
#pragma unroll
    for (int q = 0; q < 16; ++q) rsum[q] = 0.0f;
    float csum[4] = {0.0f, 0.0f, 0.0f, 0.0f};
    float psum = 0.0f;

#pragma unroll
    for (int r = 0; r < 4; ++r) {
        const int ib = rowbase + arow0 + r * 16 + lh * 4;
#pragma unroll
        for (int c = 0; c < 4; ++c) {
            const int j = colbase + bcol0 + c * 16 + lm;
#pragma unroll
            for (int q = 0; q < 4; ++q) {
                const int i = ib + q;
                const float lg = 2.0f * acc[r][c][q];
                const float e = __expf(lg);
                const float ev = (diag && (j == i)) ? 0.0f : e;
                rsum[r * 4 + q] += ev;
                csum[c] += ev;                                   // used iff !diag
                if (diag) psum += (j == (i ^ 1)) ? lg : 0.0f;
            }
        }
    }

    // row sums: reduce over the 16 lm lanes, one atomic per row
#pragma unroll
    for (int q = 0; q < 16; ++q) {
        float v = rsum[q];
        v += __shfl_xor(v, 1); v += __shfl_xor(v, 2);
        v += __shfl_xor(v, 4); v += __shfl_xor(v, 8);
        rsum[q] = v;
    }
    if (lm == 0) {
#pragma unroll
        for (int r = 0; r < 4; ++r)
#pragma unroll
            for (int q = 0; q < 4; ++q)
                atomicAdd(&rowsum[rowbase + arow0 + r * 16 + lh * 4 + q], rsum[r * 4 + q]);
    }

    if (!diag) {
        // col sums (the transposed contribution): collapse lh groups, atomic per col
#pragma unroll
        for (int c = 0; c < 4; ++c) {
            float v = csum[c];
            v += __shfl_xor(v, 16); v += __shfl_xor(v, 32);
            if (lh == 0) atomicAdd(&rowsum[colbase + bcol0 + c * 16 + lm], v);
        }
    } else {
        // positive-pair block reduce -> possum[rt]
        float p = psum;
        p += __shfl_xor(p, 1);  p += __shfl_xor(p, 2);  p += __shfl_xor(p, 4);
        p += __shfl_xor(p, 8);  p += __shfl_xor(p, 16); p += __shfl_xor(p, 32);
        if (l == 0) psh[w] = p;
        __syncthreads();
        if (t == 0) possum[rt] = psh[0] + psh[1] + psh[2] + psh[3];
    }
}

// ---------------- kernel 3: final scalar ----------------
__global__ __launch_bounds__(512) void ntxent_final(const float* __restrict__ rowsum,
                                                    const float* __restrict__ possum,
                                                    float* __restrict__ out)
{
    __shared__ float sh[8];
    const int t = threadIdx.x;
    float s = 0.0f;
#pragma unroll
    for (int r = 0; r < 16; ++r) s += __logf(rowsum[r * 512 + t]);  // ILP: 16 indep loads
    if (t < 64) s -= possum[t];
    s += __shfl_xor(s, 1);  s += __shfl_xor(s, 2);  s += __shfl_xor(s, 4);
    s += __shfl_xor(s, 8);  s += __shfl_xor(s, 16); s += __shfl_xor(s, 32);
    if ((t & 63) == 0) sh[t >> 6] = s;
    __syncthreads();
    if (t == 0) {
        float a = 0.0f;
#pragma unroll
        for (int k = 0; k < 8; ++k) a += sh[k];
        out[0] = a * (1.0f / NN);
    }
}

extern "C" void kernel_launch(void* const* d_in, const int* in_sizes, int n_in,
                              void* d_out, int out_size, void* d_ws, size_t ws_size,
                              hipStream_t stream)
{
    const float* z = (const float*)d_in[0];
    char*  znB    = (char*)d_ws;
    float* rowsum = (float*)((char*)d_ws + (size_t)NN * 512);
    float* possum = (float*)((char*)d_ws + (size_t)NN * 512 + (size_t)NN * 4);
    float* out = (float*)d_out;

    ntxent_norm <<<dim3(NN / 4), dim3(256), 0, stream>>>(z, znB, rowsum);
    ntxent_sim  <<<dim3(2080),   dim3(256), 0, stream>>>(znB, rowsum, possum);
    ntxent_final<<<dim3(1),      dim3(512), 0, stream>>>(rowsum, possum, out);
}

// Round 6
// 64.450 us; speedup vs baseline: 1.8954x; 1.2079x over previous
//
#include <hip/hip_runtime.h>

#define NN 8192
#define DD 256   // 512 bytes per bf16 row

typedef __bf16 bf16x8 __attribute__((ext_vector_type(8)));
typedef float  f32x4  __attribute__((ext_vector_type(4)));

__device__ __forceinline__ unsigned short f2bf(float f) {
    unsigned u = __float_as_uint(f);
    return (unsigned short)((u + 0x7fffu + ((u >> 16) & 1u)) >> 16);
}

__device__ __forceinline__ void gload16(const void* g, void* l) {
    __builtin_amdgcn_global_load_lds((const __attribute__((address_space(1))) void*)g,
                                     (__attribute__((address_space(3))) void*)l,
                                     16, 0, 0);
}

// ---------------- kernel 1: normalize rows -> bf16, zero rowsum ----------------
__global__ __launch_bounds__(256) void ntxent_norm(const float* __restrict__ z,
                                                   char* __restrict__ znB,
                                                   float* __restrict__ rowsum)
{
    const int t = threadIdx.x;
    const int l = t & 63;
    const int w = t >> 6;
    const int row = blockIdx.x * 4 + w;

    float4 v = ((const float4*)(z + (size_t)row * DD))[l];
    float ss = v.x * v.x + v.y * v.y + v.z * v.z + v.w * v.w;
    ss += __shfl_xor(ss, 1);  ss += __shfl_xor(ss, 2);  ss += __shfl_xor(ss, 4);
    ss += __shfl_xor(ss, 8);  ss += __shfl_xor(ss, 16); ss += __shfl_xor(ss, 32);
    const float inv = 1.0f / fmaxf(sqrtf(ss), 1e-8f);

    uint2 o;
    o.x = (unsigned)f2bf(v.x * inv) | ((unsigned)f2bf(v.y * inv) << 16);
    o.y = (unsigned)f2bf(v.z * inv) | ((unsigned)f2bf(v.w * inv) << 16);
    ((uint2*)(znB + (size_t)row * 512))[l] = o;

    if (blockIdx.x < 32) rowsum[blockIdx.x * 256 + t] = 0.0f;
}

// ---------------- kernel 2: symmetric triangle, 2 tiles per block ----------------
// 2080 lower-triangle 128x128 tiles of the symmetric sim matrix, 2 consecutive
// tiles per block -> 1040 blocks x 8 K-steps (R1's proven depth/overlap regime).
// Off-diag tile: e_ij feeds rowsum_i (row reduce) AND rowsum_j (col reduce).
// Diag tile: full tile, self-mask, positive pairs. Inner loop is R1's verbatim
// 2-barrier 128x128/BK=64 XOR-swizzled machinery (measured 0 bank conflicts).
__global__ __launch_bounds__(256) void ntxent_sim(const char* __restrict__ znB,
                                                  float* __restrict__ rowsum,
                                                  float* __restrict__ possum)
{
    __shared__ char sA[16384];   // 128 rows x 128B (BK=64 bf16), XOR-swizzled
    __shared__ char sB[16384];
    __shared__ float psh[4];

    const int t  = threadIdx.x;
    const int l  = t & 63;
    const int w  = t >> 6;      // wave 0..3
    const int wr = w >> 1;      // row half
    const int wc = w & 1;       // col half
    const int lm = l & 15;
    const int lh = l >> 4;      // 0..3

    const int arow0 = wr * 64;
    const int bcol0 = wc * 64;
    const f32x4 vzero = {0.0f, 0.0f, 0.0f, 0.0f};

#pragma unroll 1
    for (int half = 0; half < 2; ++half) {
        const int tile = blockIdx.x * 2 + half;

        // triangular tile -> (rt, ct), rt >= ct  (block-uniform scalar math)
        int rt = (int)((sqrtf(8.0f * (float)tile + 1.0f) - 1.0f) * 0.5f);
        while ((rt + 1) * (rt + 2) / 2 <= tile) ++rt;
        while (rt * (rt + 1) / 2 > tile) --rt;
        const int ct = tile - rt * (rt + 1) / 2;
        const int rowbase = rt * 128;
        const int colbase = ct * 128;
        const bool diag = (rt == ct);

        f32x4 acc[4][4];
#pragma unroll
        for (int r = 0; r < 4; ++r)
#pragma unroll
            for (int c = 0; c < 4; ++c) acc[r][c] = vzero;

#pragma unroll 1
        for (int bk = 0; bk < 4; ++bk) {
            __syncthreads();   // all waves done reading sA/sB from previous step
#pragma unroll
            for (int p = 0; p < 4; ++p) {
                const int flat = p * 4096 + t * 16;
                const int row = flat >> 7;
                const int kb  = flat & 127;
                const int skb = (kb ^ ((row & 7) << 4));
                gload16(znB + (size_t)(rowbase + row) * 512 + bk * 128 + skb, sA + flat);
                gload16(znB + (size_t)(colbase + row) * 512 + bk * 128 + skb, sB + flat);
            }
            asm volatile("s_waitcnt vmcnt(0)" ::: "memory");
            __syncthreads();
#pragma unroll
            for (int kw = 0; kw < 2; ++kw) {
                const int kt = kw * 64 + lh * 16;   // byte offset within BK chunk
                bf16x8 af[4], bfr[4];
#pragma unroll
                for (int s = 0; s < 4; ++s) {
                    const int ar = arow0 + s * 16 + lm;
                    af[s]  = *(const bf16x8*)(sA + ar * 128 + (kt ^ ((ar & 7) << 4)));
                    const int bc = bcol0 + s * 16 + lm;
                    bfr[s] = *(const bf16x8*)(sB + bc * 128 + (kt ^ ((bc & 7) << 4)));
                }
#pragma unroll
                for (int r = 0; r < 4; ++r)
#pragma unroll
                    for (int c = 0; c < 4; ++c)
                        acc[r][c] = __builtin_amdgcn_mfma_f32_16x16x32_bf16(af[r], bfr[c], acc[r][c], 0, 0, 0);
            }
        }

        // ---------------- epilogue: exp, row sums, col sums (symmetry), positives ----
        float rsum[16];
#pragma unroll
        for (int q = 0; q < 16; ++q) rsum[q] = 0.0f;
        float csum[4] = {0.0f, 0.0f, 0.0f, 0.0f};
        float psum = 0.0f;

#pragma unroll
        for (int r = 0; r < 4; ++r) {
            const int ib = rowbase + arow0 + r * 16 + lh * 4;
#pragma unroll
            for (int c = 0; c < 4; ++c) {
                const int j = colbase + bcol0 + c * 16 + lm;
#pragma unroll
                for (int q = 0; q < 4; ++q) {
                    const int i = ib + q;
                    const float lg = 2.0f * acc[r][c][q];
                    const float e = __expf(lg);
                    const float ev = (diag && (j == i)) ? 0.0f : e;
                    rsum[r * 4 + q] += ev;
                    csum[c] += ev;                                   // used iff !diag
                    if (diag) psum += (j == (i ^ 1)) ? lg : 0.0f;
                }
            }
        }

        // row sums: reduce over the 16 lm lanes, one atomic per row
#pragma unroll
        for (int q = 0; q < 16; ++q) {
            float v = rsum[q];
            v += __shfl_xor(v, 1); v += __shfl_xor(v, 2);
            v += __shfl_xor(v, 4); v += __shfl_xor(v, 8);
            rsum[q] = v;
        }
        if (lm == 0) {
#pragma unroll
            for (int r = 0; r < 4; ++r)
#pragma unroll
                for (int q = 0; q < 4; ++q)
                    atomicAdd(&rowsum[rowbase + arow0 + r * 16 + lh * 4 + q], rsum[r * 4 + q]);
        }

        if (!diag) {
            // col sums (the transposed contribution): collapse lh groups, atomic per col
#pragma unroll
            for (int c = 0; c < 4; ++c) {
                float v = csum[c];
                v += __shfl_xor(v, 16); v += __shfl_xor(v, 32);
                if (lh == 0) atomicAdd(&rowsum[colbase + bcol0 + c * 16 + lm], v);
            }
        } else {
            // positive-pair block reduce -> possum[rt]
            float p = psum;
            p += __shfl_xor(p, 1);  p += __shfl_xor(p, 2);  p += __shfl_xor(p, 4);
            p += __shfl_xor(p, 8);  p += __shfl_xor(p, 16); p += __shfl_xor(p, 32);
            if (l == 0) psh[w] = p;
            __syncthreads();
            if (t == 0) possum[rt] = psh[0] + psh[1] + psh[2] + psh[3];
        }
    }
}

// ---------------- kernel 3: final scalar ----------------
__global__ __launch_bounds__(512) void ntxent_final(const float* __restrict__ rowsum,
                                                    const float* __restrict__ possum,
                                                    float* __restrict__ out)
{
    __shared__ float sh[8];
    const int t = threadIdx.x;
    float s = 0.0f;
#pragma unroll
    for (int r = 0; r < 16; ++r) s += __logf(rowsum[r * 512 + t]);  // ILP: 16 indep loads
    if (t < 64) s -= possum[t];
    s += __shfl_xor(s, 1);  s += __shfl_xor(s, 2);  s += __shfl_xor(s, 4);
    s += __shfl_xor(s, 8);  s += __shfl_xor(s, 16); s += __shfl_xor(s, 32);
    if ((t & 63) == 0) sh[t >> 6] = s;
    __syncthreads();
    if (t == 0) {
        float a = 0.0f;
#pragma unroll
        for (int k = 0; k < 8; ++k) a += sh[k];
        out[0] = a * (1.0f / NN);
    }
}

extern "C" void kernel_launch(void* const* d_in, const int* in_sizes, int n_in,
                              void* d_out, int out_size, void* d_ws, size_t ws_size,
                              hipStream_t stream)
{
    const float* z = (const float*)d_in[0];
    char*  znB    = (char*)d_ws;
    float* rowsum = (float*)((char*)d_ws + (size_t)NN * 512);
    float* possum = (float*)((char*)d_ws + (size_t)NN * 512 + (size_t)NN * 4);
    float* out = (float*)d_out;

    ntxent_norm <<<dim3(NN / 4), dim3(256), 0, stream>>>(z, znB, rowsum);
    ntxent_sim  <<<dim3(1040),   dim3(256), 0, stream>>>(znB, rowsum, possum);
    ntxent_final<<<dim3(1),      dim3(512), 0, stream>>>(rowsum, possum, out);
}

// Round 7
// 53.916 us; speedup vs baseline: 2.2657x; 1.1954x over previous
//
#include <hip/hip_runtime.h>

#define NN 8192
#define DD 256   // 512 bytes per bf16 row
#define NTILES 2080
#define NBLK 512

typedef __bf16 bf16x8 __attribute__((ext_vector_type(8)));
typedef float  f32x4  __attribute__((ext_vector_type(4)));

__device__ __forceinline__ unsigned short f2bf(float f) {
    unsigned u = __float_as_uint(f);
    return (unsigned short)((u + 0x7fffu + ((u >> 16) & 1u)) >> 16);
}

__device__ __forceinline__ void gload16(const void* g, void* l) {
    __builtin_amdgcn_global_load_lds((const __attribute__((address_space(1))) void*)g,
                                     (__attribute__((address_space(3))) void*)l,
                                     16, 0, 0);
}

// ---------------- kernel 1: normalize rows -> bf16, zero rowsum ----------------
__global__ __launch_bounds__(256) void ntxent_norm(const float* __restrict__ z,
                                                   char* __restrict__ znB,
                                                   float* __restrict__ rowsum)
{
    const int t = threadIdx.x;
    const int l = t & 63;
    const int w = t >> 6;
    const int row = blockIdx.x * 4 + w;

    float4 v = ((const float4*)(z + (size_t)row * DD))[l];
    float ss = v.x * v.x + v.y * v.y + v.z * v.z + v.w * v.w;
    ss += __shfl_xor(ss, 1);  ss += __shfl_xor(ss, 2);  ss += __shfl_xor(ss, 4);
    ss += __shfl_xor(ss, 8);  ss += __shfl_xor(ss, 16); ss += __shfl_xor(ss, 32);
    const float inv = 1.0f / fmaxf(sqrtf(ss), 1e-8f);

    uint2 o;
    o.x = (unsigned)f2bf(v.x * inv) | ((unsigned)f2bf(v.y * inv) << 16);
    o.y = (unsigned)f2bf(v.z * inv) | ((unsigned)f2bf(v.w * inv) << 16);
    ((uint2*)(znB + (size_t)row * 512))[l] = o;

    if (blockIdx.x < 32) rowsum[blockIdx.x * 256 + t] = 0.0f;
}

// ---------------- kernel 2: symmetric triangle, continuous 2-phase pipeline ----------------
// 2080 lower-triangle 128x128 tiles; 512 blocks, each a contiguous run of 4-5 tiles.
// Double-buffered LDS (2 x 32 KB); per K-step: issue STAGE(next chunk) FIRST, compute
// current buf, then ONE vmcnt(0)+barrier (each wave drains its own loads before the
// barrier -> staged data visible to all; buf^1 readers finished behind previous barrier).
// Pipeline runs continuously across tiles. Tile body/swizzle/epilogue = R6 verbatim.
__global__ __launch_bounds__(256) void ntxent_sim(const char* __restrict__ znB,
                                                  float* __restrict__ rowsum,
                                                  float* __restrict__ possum)
{
    __shared__ char sA[2][16384];   // 128 rows x 128B (BK=64), XOR-swizzled
    __shared__ char sB[2][16384];
    __shared__ float psh[4];

    const int t  = threadIdx.x;
    const int l  = t & 63;
    const int w  = t >> 6;      // wave 0..3
    const int wr = w >> 1;      // row half
    const int wc = w & 1;       // col half
    const int lm = l & 15;
    const int lh = l >> 4;      // 0..3

    const int arow0 = wr * 64;
    const int bcol0 = wc * 64;
    const f32x4 vzero = {0.0f, 0.0f, 0.0f, 0.0f};

    // contiguous tile range [t0, t1) for this block
    const int t0 = (NTILES * blockIdx.x) >> 9;
    const int t1 = (NTILES * (blockIdx.x + 1)) >> 9;

    // t0 -> (rt, ct), rt >= ct
    int rt = (int)((sqrtf(8.0f * (float)t0 + 1.0f) - 1.0f) * 0.5f);
    while ((rt + 1) * (rt + 2) / 2 <= t0) ++rt;
    while (rt * (rt + 1) / 2 > t0) --rt;
    int ct = t0 - rt * (rt + 1) / 2;

    auto STAGE = [&](int buf, int rowbase, int colbase, int bk) {
#pragma unroll
        for (int p = 0; p < 4; ++p) {
            const int flat = p * 4096 + t * 16;
            const int row = flat >> 7;
            const int kb  = flat & 127;
            const int skb = (kb ^ ((row & 7) << 4));
            gload16(znB + (size_t)(rowbase + row) * 512 + bk * 128 + skb, &sA[buf][flat]);
            gload16(znB + (size_t)(colbase + row) * 512 + bk * 128 + skb, &sB[buf][flat]);
        }
    };

    int buf = 0;
    // prologue: stage first chunk of first tile
    STAGE(0, rt * 128, ct * 128, 0);
    asm volatile("s_waitcnt vmcnt(0)" ::: "memory");
    __syncthreads();

#pragma unroll 1
    for (int tl = t0; tl < t1; ++tl) {
        const int rowbase = rt * 128;
        const int colbase = ct * 128;
        const bool diag = (rt == ct);
        // next tile coords (triangle walk)
        const int nrt = (ct < rt) ? rt : rt + 1;
        const int nct = (ct < rt) ? ct + 1 : 0;

        f32x4 acc[4][4];
#pragma unroll
        for (int r = 0; r < 4; ++r)
#pragma unroll
            for (int c = 0; c < 4; ++c) acc[r][c] = vzero;

#pragma unroll 1
        for (int bk = 0; bk < 4; ++bk) {
            // issue next chunk's stage BEFORE computing current chunk
            if (bk < 3)            STAGE(buf ^ 1, rowbase, colbase, bk + 1);
            else if (tl + 1 < t1)  STAGE(buf ^ 1, nrt * 128, nct * 128, 0);

#pragma unroll
            for (int kw = 0; kw < 2; ++kw) {
                const int kt = kw * 64 + lh * 16;
                bf16x8 af[4], bfr[4];
#pragma unroll
                for (int s = 0; s < 4; ++s) {
                    const int ar = arow0 + s * 16 + lm;
                    af[s]  = *(const bf16x8*)(&sA[buf][ar * 128 + (kt ^ ((ar & 7) << 4))]);
                    const int bc = bcol0 + s * 16 + lm;
                    bfr[s] = *(const bf16x8*)(&sB[buf][bc * 128 + (kt ^ ((bc & 7) << 4))]);
                }
#pragma unroll
                for (int r = 0; r < 4; ++r)
#pragma unroll
                    for (int c = 0; c < 4; ++c)
                        acc[r][c] = __builtin_amdgcn_mfma_f32_16x16x32_bf16(af[r], bfr[c], acc[r][c], 0, 0, 0);
            }

            // single drain: my loads done -> barrier -> staged buf^1 visible to all
            asm volatile("s_waitcnt vmcnt(0)" ::: "memory");
            __syncthreads();
            buf ^= 1;
        }

        // ---------------- epilogue: exp, row sums, col sums (symmetry), positives ----
        float rsum[16];
#pragma unroll
        for (int q = 0; q < 16; ++q) rsum[q] = 0.0f;
        float csum[4] = {0.0f, 0.0f, 0.0f, 0.0f};
        float psum = 0.0f;

#pragma unroll
        for (int r = 0; r < 4; ++r) {
            const int ib = rowbase + arow0 + r * 16 + lh * 4;
#pragma unroll
            for (int c = 0; c < 4; ++c) {
                const int j = colbase + bcol0 + c * 16 + lm;
#pragma unroll
                for (int q = 0; q < 4; ++q) {
                    const int i = ib + q;
                    const float lg = 2.0f * acc[r][c][q];
                    const float e = __expf(lg);
                    const float ev = (diag && (j == i)) ? 0.0f : e;
                    rsum[r * 4 + q] += ev;
                    csum[c] += ev;                                   // used iff !diag
                    if (diag) psum += (j == (i ^ 1)) ? lg : 0.0f;
                }
            }
        }

        // row sums: reduce over the 16 lm lanes, one atomic per row
#pragma unroll
        for (int q = 0; q < 16; ++q) {
            float v = rsum[q];
            v += __shfl_xor(v, 1); v += __shfl_xor(v, 2);
            v += __shfl_xor(v, 4); v += __shfl_xor(v, 8);
            rsum[q] = v;
        }
        if (lm == 0) {
#pragma unroll
            for (int r = 0; r < 4; ++r)
#pragma unroll
                for (int q = 0; q < 4; ++q)
                    atomicAdd(&rowsum[rowbase + arow0 + r * 16 + lh * 4 + q], rsum[r * 4 + q]);
        }

        if (!diag) {
            // col sums (transposed contribution): collapse lh groups, atomic per col
#pragma unroll
            for (int c = 0; c < 4; ++c) {
                float v = csum[c];
                v += __shfl_xor(v, 16); v += __shfl_xor(v, 32);
                if (lh == 0) atomicAdd(&rowsum[colbase + bcol0 + c * 16 + lm], v);
            }
        } else {
            // positive-pair block reduce -> possum[rt]
            float p = psum;
            p += __shfl_xor(p, 1);  p += __shfl_xor(p, 2);  p += __shfl_xor(p, 4);
            p += __shfl_xor(p, 8);  p += __shfl_xor(p, 16); p += __shfl_xor(p, 32);
            if (l == 0) psh[w] = p;
            __syncthreads();
            if (t == 0) possum[rt] = psh[0] + psh[1] + psh[2] + psh[3];
            __syncthreads();   // protect psh before any later diag tile reuses it
        }

        rt = nrt; ct = nct;
    }
}

// ---------------- kernel 3: final scalar ----------------
__global__ __launch_bounds__(512) void ntxent_final(const float* __restrict__ rowsum,
                                                    const float* __restrict__ possum,
                                                    float* __restrict__ out)
{
    __shared__ float sh[8];
    const int t = threadIdx.x;
    float s = 0.0f;
#pragma unroll
    for (int r = 0; r < 16; ++r) s += __logf(rowsum[r * 512 + t]);  // ILP: 16 indep loads
    if (t < 64) s -= possum[t];
    s += __shfl_xor(s, 1);  s += __shfl_xor(s, 2);  s += __shfl_xor(s, 4);
    s += __shfl_xor(s, 8);  s += __shfl_xor(s, 16); s += __shfl_xor(s, 32);
    if ((t & 63) == 0) sh[t >> 6] = s;
    __syncthreads();
    if (t == 0) {
        float a = 0.0f;
#pragma unroll
        for (int k = 0; k < 8; ++k) a += sh[k];
        out[0] = a * (1.0f / NN);
    }
}

extern "C" void kernel_launch(void* const* d_in, const int* in_sizes, int n_in,
                              void* d_out, int out_size, void* d_ws, size_t ws_size,
                              hipStream_t stream)
{
    const float* z = (const float*)d_in[0];
    char*  znB    = (char*)d_ws;
    float* rowsum = (float*)((char*)d_ws + (size_t)NN * 512);
    float* possum = (float*)((char*)d_ws + (size_t)NN * 512 + (size_t)NN * 4);
    float* out = (float*)d_out;

    ntxent_norm <<<dim3(NN / 4), dim3(256), 0, stream>>>(z, znB, rowsum);
    ntxent_sim  <<<dim3(NBLK),   dim3(256), 0, stream>>>(znB, rowsum, possum);
    ntxent_final<<<dim3(1),      dim3(512), 0, stream>>>(rowsum, possum, out);
}